// Round 12
// baseline (531.008 us; speedup 1.0000x reference)
//
#include <hip/hip_runtime.h>
#include <hip/hip_bf16.h>
#include <cmath>
#include <cfloat>

#define BATCH 4
#define NPTS 8192
#define NPOINT 409
#define NBALLS (BATCH * NPOINT)   // 1636
#define REP_NS 20
#define REP_QB 64                 // queries per block
#define REP_SEG 8                 // segments per query scan (one per wave)
#define SEG_LEN (NPTS / REP_SEG)  // 1024
#define REP_BLOCKS (BATCH * NPTS / REP_QB)  // 512

#define WCAP 160                  // per-wave hit capacity (E[hits]~9; huge margin)
#define HCAP (4 * WCAP)           // 640

// ws layout (bytes):
//   [0, 6544)       : fps_idx  int[1636]
//   [8192, 12288)   : rep_part double[512]
//   [12288, 25376)  : uni_part double[1636]
#define WS_FPS_OFF 0
#define WS_REP_OFF 8192
#define WS_UNI_OFF 12288

typedef float v2f __attribute__((ext_vector_type(2)));

struct UniParams {
  float  thr[5];
  float  e[5];
  float  eden[5];
  int    ns[5];
};

// u64 max-combine with a DPP-shifted copy (gfx9 rocPRIM wave64 reduce pattern)
template <int CTRL>
__device__ __forceinline__ unsigned long long dpp_max_u64(unsigned long long key) {
  const int lo = __builtin_amdgcn_update_dpp(
      0, (int)(unsigned)(key & 0xFFFFFFFFull), CTRL, 0xf, 0xf, true);
  const int hi = __builtin_amdgcn_update_dpp(
      0, (int)(unsigned)(key >> 32), CTRL, 0xf, 0xf, true);
  const unsigned long long ok =
      ((unsigned long long)(unsigned)hi << 32) | (unsigned)lo;
  return ok > key ? ok : key;
}

// ---------------------------------------------------------------- repulsion helpers
__device__ __forceinline__ void ins5(float v, float& t0, float& t1, float& t2,
                                     float& t3, float& t4) {
  if (v < t4) {
    t4 = v;
    if (t4 < t3) { float tmp = t3; t3 = t4; t4 = tmp; }
    if (t3 < t2) { float tmp = t2; t2 = t3; t3 = tmp; }
    if (t2 < t1) { float tmp = t1; t1 = t2; t2 = tmp; }
    if (t1 < t0) { float tmp = t0; t0 = t1; t1 = tmp; }
  }
}

__device__ __forceinline__ float rep_term(float d) {
  d = fmaxf(d, 0.0f);
  return 0.07f - sqrtf(d) * expf(-(d / 0.0009f));
}

// ---------------------------------------------------------------- fused fps+rep
// blocks [0, BATCH)            : FPS, one block per batch, 512 threads.
//   Coords live in LDS in a PAIR-TRANSPOSED layout:
//     Xp[k*1024 + 2*tid + j] = x of point (tid*16 + 2k + j),  k<8, j<2
//   so the step loop reads ds_read_b64 at lane-stride-2 dwords — the b64
//   structural floor (all 32 banks, 4 dwords each), no excess conflict.
//   R10 (stride-16: 32-way, 8.8M conflicts) and R8-R11 (compiler remats
//   coords from L2/scratch each step; VGPR=44 proves regs never held them)
//   are both fixed: the loop touches only LDS + VGPR dist[8].
// blocks [BATCH, +REP_BLOCKS)  : repulsion, 64 queries x 8 segments.
__global__ __launch_bounds__(512, 2) void fpsrep_kernel(const float* __restrict__ pcd,
                                                        int* __restrict__ fps_idx,
                                                        double* __restrict__ rep_part,
                                                        float rep_thr) {
  const int tid = threadIdx.x;
  const int lane = tid & 63;
  const int w = tid >> 6;
  extern __shared__ float smem[];   // 96 KB: Xp[8192] Yp[8192] Zp[8192]

  if (blockIdx.x < BATCH) {
    // ---------------- FPS ----------------
    const int b = blockIdx.x;
    const float* P = pcd + b * NPTS * 3;
    float* Xp = smem;
    float* Yp = smem + NPTS;
    float* Zp = smem + 2 * NPTS;

    const int base = tid * 16;
#pragma unroll
    for (int k = 0; k < 8; k++) {
      const int i0 = (base + 2 * k) * 3;
      const int i1 = (base + 2 * k + 1) * 3;
      const int a = k * 1024 + 2 * tid;
      *(v2f*)&Xp[a] = (v2f){P[i0 + 0], P[i1 + 0]};
      *(v2f*)&Yp[a] = (v2f){P[i0 + 1], P[i1 + 1]};
      *(v2f*)&Zp[a] = (v2f){P[i0 + 2], P[i1 + 2]};
    }

    v2f dist[8];
#pragma unroll
    for (int k = 0; k < 8; k++) dist[k] = (v2f){1e10f, 1e10f};

    __shared__ unsigned long long s_key[2][8];   // ping-pong slots
    __syncthreads();

    int far = 0;
    float fx = Xp[0], fy = Yp[0], fz = Zp[0];
    for (int s = 0; s < NPOINT; s++) {
      if (tid == 0) fps_idx[b * NPOINT + s] = far;

      const v2f fxv = (v2f){fx, fx};
      const v2f fyv = (v2f){fy, fy};
      const v2f fzv = (v2f){fz, fz};
      float best = -1.0f;
      int kb = 0;
#pragma unroll
      for (int k = 0; k < 8; k++) {
#pragma clang fp contract(off)
        const int a = k * 1024 + 2 * tid;
        const v2f xx = *(const v2f*)&Xp[a];      // b64, stride-2: conflict-floor
        const v2f yy = *(const v2f*)&Yp[a];
        const v2f zz = *(const v2f*)&Zp[a];
        const v2f dx = xx - fxv;
        const v2f dy = yy - fyv;
        const v2f dz = zz - fzv;
        const v2f d  = (dx * dx + dy * dy) + dz * dz;
        const float n0 = fminf(dist[k].x, d.x);
        const float n1 = fminf(dist[k].y, d.y);
        dist[k].x = n0;
        dist[k].y = n1;
        if (n0 > best) { best = n0; kb = 2 * k; }       // ascending: first occurrence
        if (n1 > best) { best = n1; kb = 2 * k + 1; }
      }
      const int bidx = base + kb;
      // best >= 0 (squared distances): u64 key ordering == (dist, -idx)
      unsigned long long key =
          ((unsigned long long)__float_as_uint(best) << 32) |
          (unsigned long long)(0xFFFFFFFFu - (unsigned)bidx);

      key = dpp_max_u64<0x111>(key);   // row_shr:1
      key = dpp_max_u64<0x112>(key);   // row_shr:2
      key = dpp_max_u64<0x114>(key);   // row_shr:4
      key = dpp_max_u64<0x118>(key);   // row_shr:8
      key = dpp_max_u64<0x142>(key);   // row_bcast:15
      key = dpp_max_u64<0x143>(key);   // row_bcast:31

      const int par = s & 1;
      if (lane == 63) s_key[par][w] = key;
      __syncthreads();
      unsigned long long kbk = s_key[par][0];
#pragma unroll
      for (int w2 = 1; w2 < 8; w2++) {
        const unsigned long long kk = s_key[par][w2];
        if (kk > kbk) kbk = kk;
      }
      far = (int)(0xFFFFFFFFu - (unsigned)(kbk & 0xFFFFFFFFull));
      // far point coords: wave-uniform LDS broadcast (conflict-free)
      const int fa = ((far & 15) >> 1) * 1024 + 2 * (far >> 4) + (far & 1);
      fx = Xp[fa];
      fy = Yp[fa];
      fz = Zp[fa];
    }
    return;
  }

  // ---------------- repulsion ----------------
  __shared__ float s_t5[REP_SEG][REP_QB][5];
  __shared__ float s_d0[REP_SEG][REP_QB];
  __shared__ int   s_cnt[REP_SEG][REP_QB];

  const int blk = blockIdx.x - BATCH;
  const int b = blk >> 7;                       // 128 blocks per batch
  const int q = ((blk & 127) << 6) + lane;
  const float* P = pcd + b * NPTS * 3;

  const float qx = P[q * 3 + 0], qy = P[q * 3 + 1], qz = P[q * 3 + 2];

  int cnt = 0;
  float d0 = 0.0f;
  float t0 = FLT_MAX, t1 = FLT_MAX, t2 = FLT_MAX, t3 = FLT_MAX, t4 = FLT_MAX;

  const int wu = __builtin_amdgcn_readfirstlane(w);
  const float* S = P + wu * SEG_LEN * 3;
#pragma unroll 4
  for (int i = 0; i < SEG_LEN; i++) {
    const float x = S[i * 3 + 0];               // uniform addr -> scalar loads
    const float y = S[i * 3 + 1];
    const float z = S[i * 3 + 2];
    const float dx = qx - x, dy = qy - y, dz = qz - z;
    const float d = dx * dx + dy * dy + dz * dz;
    if (d <= rep_thr && cnt < REP_NS) {
      if (cnt == 0) d0 = d;
      ins5(d, t0, t1, t2, t3, t4);
      cnt++;
    }
  }

  s_t5[w][lane][0] = t0; s_t5[w][lane][1] = t1; s_t5[w][lane][2] = t2;
  s_t5[w][lane][3] = t3; s_t5[w][lane][4] = t4;
  s_d0[w][lane] = d0;
  s_cnt[w][lane] = cnt;
  __syncthreads();

  if (w == 0) {
    int total = 0;
    float fd0 = 0.0f;
    int first_seen = 0;
    float m0 = FLT_MAX, m1 = FLT_MAX, m2 = FLT_MAX, m3 = FLT_MAX, m4 = FLT_MAX;
#pragma unroll
    for (int sg = 0; sg < REP_SEG; sg++) {
      const int c = s_cnt[sg][lane];
      if (c > 0 && !first_seen) { fd0 = s_d0[sg][lane]; first_seen = 1; }
      total += c;
#pragma unroll
      for (int j = 0; j < 5; j++) ins5(s_t5[sg][lane][j], m0, m1, m2, m3, m4);
    }

    if (total > REP_NS) {
      // cap binds across segments (astronomically rare): exact rescan
      int c2 = 0;
      m0 = FLT_MAX; m1 = FLT_MAX; m2 = FLT_MAX; m3 = FLT_MAX; m4 = FLT_MAX;
      for (int i = 0; i < NPTS && c2 < REP_NS; i++) {
        const float dx = qx - P[i * 3 + 0];
        const float dy = qy - P[i * 3 + 1];
        const float dz = qz - P[i * 3 + 2];
        const float d = dx * dx + dy * dy + dz * dz;
        if (d <= rep_thr) { ins5(d, m0, m1, m2, m3, m4); c2++; }
      }
    } else {
      for (int c = total; c < REP_NS; c++) ins5(fd0, m0, m1, m2, m3, m4);
    }

    float sum = rep_term(m1) + rep_term(m2) + rep_term(m3) + rep_term(m4);
#pragma unroll
    for (int off = 32; off >= 1; off >>= 1) sum += __shfl_down(sum, off);
    if (lane == 0) rep_part[blk] = (double)sum;
  }
}

// ---------------------------------------------------------------- uniform
// One ball per block. Single scan vs thr[4] (lists are nested); per-wave
// ordered compaction -> concat (index order preserved). Each wave owns a
// percentage jp (wave 0: jp 0 and 4); lanes own rows in parallel. Pads are
// copies of member 0 => pad rows + row 0 have second-smallest exactly 0.
__global__ __launch_bounds__(256) void uni_kernel(const float* __restrict__ pcd,
                                                  const int* __restrict__ fps_idx,
                                                  double* __restrict__ uni_part,
                                                  UniParams up) {
  const int ball = blockIdx.x;
  const int b = ball / NPOINT;
  const int tid = threadIdx.x;
  const int lane = tid & 63, w = tid >> 6;
  const float* P = pcd + b * NPTS * 3;

  const int qidx = fps_idx[ball];
  const float qx = P[qidx * 3 + 0], qy = P[qidx * 3 + 1], qz = P[qidx * 3 + 2];

  __shared__ float wx[4][WCAP], wy[4][WCAP], wz[4][WCAP], wd[4][WCAP];
  __shared__ int   s_wcnt[4];
  __shared__ float FX[HCAP], FY[HCAP], FZ[HCAP], FD[HCAP];
  __shared__ float CX[5][131], CY[5][131], CZ[5][131];
  __shared__ double dpart[4];

  // ---- scan this wave's contiguous 2048-point segment (index order kept)
  int wcnt = 0;
  const float* S = P + w * 2048 * 3;
  for (int it = 0; it < 32; it++) {
    const int j = it * 64 + lane;
    const float x = S[j * 3 + 0];
    const float y = S[j * 3 + 1];
    const float z = S[j * 3 + 2];
    const float dx = qx - x, dy = qy - y, dz = qz - z;
    const float d = dx * dx + dy * dy + dz * dz;
    const bool hit = (d <= up.thr[4]);
    const unsigned long long m = __ballot(hit);
    if (hit) {
      const int pos = wcnt + __popcll(m & ((1ull << lane) - 1ull));
      if (pos < WCAP) {
        wx[w][pos] = x; wy[w][pos] = y; wz[w][pos] = z; wd[w][pos] = d;
      }
    }
    wcnt += __popcll(m);
  }
  if (lane == 0) s_wcnt[w] = min(wcnt, WCAP);
  __syncthreads();

  // ---- concat (wave segments are ascending index ranges)
  int off = 0;
#pragma unroll
  for (int w2 = 0; w2 < 4; w2++) {
    if (w2 == w) break;
    off += s_wcnt[w2];
  }
  for (int i = lane; i < s_wcnt[w]; i += 64) {
    FX[off + i] = wx[w][i]; FY[off + i] = wy[w][i];
    FZ[off + i] = wz[w][i]; FD[off + i] = wd[w][i];
  }
  __syncthreads();
  const int c = s_wcnt[0] + s_wcnt[1] + s_wcnt[2] + s_wcnt[3];   // >=1 (self hit)

  const double wj_tab[5] = {0.16 / (5.0 * 1636.0 * 32.0),
                            0.64 / (5.0 * 1636.0 * 65.0),
                            1.0  / (5.0 * 1636.0 * 81.0),
                            1.44 / (5.0 * 1636.0 * 98.0),
                            2.56 / (5.0 * 1636.0 * 131.0)};

  double local = 0.0;
  for (int jp = w; jp < 5; jp += ((w == 0) ? 4 : 8)) {
    const float thr = up.thr[jp];
    const int nsj = up.ns[jp];

    // build compact member list (first-nsj hits, index order) — wave-local
    int cnt2 = 0;
    for (int bse = 0; bse < c; bse += 64) {
      const int e = bse + lane;
      const bool pred = (e < c) && (FD[e] <= thr);
      const unsigned long long m = __ballot(pred);
      if (pred) {
        const int pos = cnt2 + __popcll(m & ((1ull << lane) - 1ull));
        if (pos < nsj) {
          CX[jp][pos] = FX[e]; CY[jp][pos] = FY[e]; CZ[jp][pos] = FZ[e];
        }
      }
      cnt2 += __popcll(m);
    }
    const int cj = min(cnt2, nsj);     // >= 1 (self hit)
    const int pads = nsj - cj;
    const int istart = (pads > 0) ? 1 : 0;

    if (pads > 0 && lane == 0) {
      // pad rows + row 0: second-smallest = 0 exactly
      const float ud = sqrtf(fabsf(1e-8f));
      const float dd = ud - up.e[jp];
      const float tt = (dd * dd) / up.eden[jp];
      local += (double)tt * wj_tab[jp] * (double)(pads + 1);
    }

    // real rows in parallel across lanes; inner reads are wave-broadcast
    for (int r = istart + lane; r < cj; r += 64) {
      const float xi = CX[jp][r], yi = CY[jp][r], zi = CZ[jp][r];
      float m2 = FLT_MAX;
      for (int e2 = 0; e2 < cj; e2++) {
        if (e2 == r) continue;
        const float dx = xi - CX[jp][e2];
        const float dy = yi - CY[jp][e2];
        const float dz = zi - CZ[jp][e2];
        const float d = dx * dx + dy * dy + dz * dz;
        if (d < m2) m2 = d;
      }
      const float ud = sqrtf(fabsf(m2 + 1e-8f));
      const float dd = ud - up.e[jp];
      const float tt = (dd * dd) / up.eden[jp];
      local += (double)tt * wj_tab[jp];
    }
  }

#pragma unroll
  for (int o = 32; o >= 1; o >>= 1) local += __shfl_down(local, o);
  if (lane == 0) dpart[w] = local;
  __syncthreads();
  if (tid == 0) {
    uni_part[ball] = dpart[0] + dpart[1] + dpart[2] + dpart[3];
  }
}

// ---------------------------------------------------------------- finalize
__global__ __launch_bounds__(256) void fin_kernel(const double* __restrict__ rep_part,
                                                  const double* __restrict__ uni_part,
                                                  float* __restrict__ out) {
  __shared__ double sd[256];
  const int t = threadIdx.x;
  double u = 0.0, r = 0.0;
  for (int i = t; i < NBALLS; i += 256) u += uni_part[i];
  for (int i = t; i < REP_BLOCKS; i += 256) r += rep_part[i];

  sd[t] = u; __syncthreads();
  for (int s = 128; s > 0; s >>= 1) { if (t < s) sd[t] += sd[t + s]; __syncthreads(); }
  const double usum = sd[0];
  __syncthreads();
  sd[t] = r; __syncthreads();
  for (int s = 128; s > 0; s >>= 1) { if (t < s) sd[t] += sd[t + s]; __syncthreads(); }

  if (t == 0) {
    out[0] = (float)usum;
    out[1] = (float)(sd[0] * (1.0 / 131072.0));
  }
}

// ---------------------------------------------------------------- launch
extern "C" void kernel_launch(void* const* d_in, const int* in_sizes, int n_in,
                              void* d_out, int out_size, void* d_ws, size_t ws_size,
                              hipStream_t stream) {
  (void)in_sizes; (void)n_in; (void)out_size; (void)ws_size;
  const float* pcd = (const float*)d_in[0];
  float* out = (float*)d_out;
  int*    fps      = (int*)((char*)d_ws + WS_FPS_OFF);
  double* rep_part = (double*)((char*)d_ws + WS_REP_OFF);
  double* uni_part = (double*)((char*)d_ws + WS_UNI_OFF);

  const float rep_thr = (float)(0.07 * 0.07);

  UniParams up;
  const double ps[5] = {0.004, 0.008, 0.01, 0.012, 0.016};
  for (int j = 0; j < 5; j++) {
    const int ns = (int)(8192.0 * ps[j]);            // 32, 65, 81, 98, 131
    const double r = sqrt(ps[j]);
    up.thr[j] = (float)(r * r);
    const double disk = M_PI * ps[j] / (double)ns;
    const double el = sqrt(2.0 * disk / 1.732);
    up.e[j] = (float)el;
    up.eden[j] = (float)(el + 1e-8);
    up.ns[j] = ns;
  }

  // 96 KB dynamic LDS for the fps transposed coord store (Xp/Yp/Zp).
  static const int kDynLds = NPTS * 3 * (int)sizeof(float);   // 98304
  (void)hipFuncSetAttribute((const void*)fpsrep_kernel,
                            hipFuncAttributeMaxDynamicSharedMemorySize, kDynLds);

  fpsrep_kernel<<<BATCH + REP_BLOCKS, 512, kDynLds, stream>>>(pcd, fps, rep_part,
                                                              rep_thr);
  uni_kernel<<<NBALLS, 256, 0, stream>>>(pcd, fps, uni_part, up);
  fin_kernel<<<1, 256, 0, stream>>>(rep_part, uni_part, out);
}

// Round 13
// 433.989 us; speedup vs baseline: 1.2236x; 1.2236x over previous
//
#include <hip/hip_runtime.h>
#include <hip/hip_bf16.h>
#include <cmath>
#include <cfloat>

#define BATCH 4
#define NPTS 8192
#define NPOINT 409
#define NBALLS (BATCH * NPOINT)   // 1636
#define REP_NS 20
#define REP_SEG 8                 // rep segments per query (one per wave)
#define SEG_LEN (NPTS / REP_SEG)  // 1024
#define REP_TASKS 512
#define NTASKS (REP_TASKS + NBALLS)   // 2148
#define NWORKERS 252

#define UW 96                     // uni per-wave hit capacity (E[hits/1024pts]~1.1)
#define UH (8 * UW)               // 768

// ws layout (bytes):
//   [0, 6544)       : fps_idx  int[1636]   (sentinel 0xFF = negative)
//   [8192, 12288)   : rep_part double[512]
//   [12288, 25376)  : uni_part double[1636]
//   [25600, 25604)  : task counter int
#define WS_FPS_OFF 0
#define WS_REP_OFF 8192
#define WS_UNI_OFF 12288
#define WS_CNT_OFF 25600

typedef float v2f __attribute__((ext_vector_type(2)));

struct UniParams {
  float  thr[5];
  float  e[5];
  float  eden[5];
  int    ns[5];
};

template <int CTRL>
__device__ __forceinline__ unsigned long long dpp_max_u64(unsigned long long key) {
  const int lo = __builtin_amdgcn_update_dpp(
      0, (int)(unsigned)(key & 0xFFFFFFFFull), CTRL, 0xf, 0xf, true);
  const int hi = __builtin_amdgcn_update_dpp(
      0, (int)(unsigned)(key >> 32), CTRL, 0xf, 0xf, true);
  const unsigned long long ok =
      ((unsigned long long)(unsigned)hi << 32) | (unsigned)lo;
  return ok > key ? ok : key;
}

__device__ __forceinline__ void ins5(float v, float& t0, float& t1, float& t2,
                                     float& t3, float& t4) {
  if (v < t4) {
    t4 = v;
    if (t4 < t3) { float tmp = t3; t3 = t4; t4 = tmp; }
    if (t3 < t2) { float tmp = t2; t2 = t3; t3 = tmp; }
    if (t2 < t1) { float tmp = t1; t1 = t2; t2 = tmp; }
    if (t1 < t0) { float tmp = t0; t0 = t1; t1 = tmp; }
  }
}

__device__ __forceinline__ float rep_term(float d) {
  d = fmaxf(d, 0.0f);
  return 0.07f - sqrtf(d) * expf(-(d / 0.0009f));
}

// ---------------------------------------------------------------- fused kernel
// 256 blocks x 512 threads, 1 block/CU (143KB LDS) => ALL blocks co-resident
// by capacity; no dispatch-order assumption.
//   blocks [0,4)   : FPS (R11-verbatim structure, 385us measured), publishes
//                    fps_idx[step] via relaxed agent-scope atomic store.
//   blocks [4,256) : persistent workers pulling 2148 tasks off an atomic
//                    counter: tasks [0,512) = repulsion, [512,2148) = uniform.
//                    uni tasks poll fps_idx[ball] (0xFF sentinel) — ball i
//                    unlocks at fps step i, so uni rides under fps's wall.
__global__ __launch_bounds__(512, 2) void fused_kernel(const float* __restrict__ pcd,
                                                       int* __restrict__ fps_idx,
                                                       double* __restrict__ rep_part,
                                                       double* __restrict__ uni_part,
                                                       int* __restrict__ counter,
                                                       UniParams up, float rep_thr) {
  const int tid = threadIdx.x;
  const int lane = tid & 63;
  const int w = tid >> 6;
  extern __shared__ float smem[];   // 96 KB: X[8192] Y[8192] Z[8192] (fps only)

  // static shared (distinct storage per phase; no unions -> no cross-task races)
  __shared__ unsigned long long s_key[2][8];
  __shared__ float s_t5[REP_SEG][64][5];
  __shared__ float s_d0[REP_SEG][64];
  __shared__ int   s_cnt[REP_SEG][64];
  __shared__ float wx[8][UW], wy[8][UW], wz[8][UW], wd[8][UW];
  __shared__ int   s_wcnt[8];
  __shared__ float FX[UH], FY[UH], FZ[UH], FD[UH];
  __shared__ float CX[5][131], CY[5][131], CZ[5][131];
  __shared__ double dpart[8];
  __shared__ int s_task, s_qidx;

  if (blockIdx.x < BATCH) {
    // ---------------- FPS (R11 verbatim, + agent-scope publish) ----------------
    const int b = blockIdx.x;
    const float* P = pcd + b * NPTS * 3;
    float* X = smem;
    float* Y = smem + NPTS;
    float* Z = smem + 2 * NPTS;

    for (int i = tid; i < NPTS; i += 512) {
      X[i] = P[i * 3 + 0];
      Y[i] = P[i * 3 + 1];
      Z[i] = P[i * 3 + 2];
    }

    v2f px[8], py[8], pz[8], dist[8];
    const int base = tid * 16;
#pragma unroll
    for (int k = 0; k < 8; k++) {
      const int i0 = (base + 2 * k) * 3;
      const int i1 = (base + 2 * k + 1) * 3;
      px[k] = (v2f){P[i0 + 0], P[i1 + 0]};
      py[k] = (v2f){P[i0 + 1], P[i1 + 1]};
      pz[k] = (v2f){P[i0 + 2], P[i1 + 2]};
      dist[k] = (v2f){1e10f, 1e10f};
    }
#pragma unroll
    for (int k = 0; k < 8; k++) {
      asm volatile("" : "+v"(px[k]), "+v"(py[k]), "+v"(pz[k]));
    }

    __syncthreads();

    int far = 0;
    float fx = X[0], fy = Y[0], fz = Z[0];
    for (int s = 0; s < NPOINT; s++) {
      if (tid == 0) {
        __hip_atomic_store(&fps_idx[b * NPOINT + s], far,
                           __ATOMIC_RELAXED, __HIP_MEMORY_SCOPE_AGENT);
      }

      const v2f fxv = (v2f){fx, fx};
      const v2f fyv = (v2f){fy, fy};
      const v2f fzv = (v2f){fz, fz};
      float best = -1.0f;
      int kb = 0;
#pragma unroll
      for (int k = 0; k < 8; k++) {
#pragma clang fp contract(off)
        const v2f dx = px[k] - fxv;
        const v2f dy = py[k] - fyv;
        const v2f dz = pz[k] - fzv;
        const v2f d  = (dx * dx + dy * dy) + dz * dz;
        const float n0 = fminf(dist[k].x, d.x);
        const float n1 = fminf(dist[k].y, d.y);
        dist[k].x = n0;
        dist[k].y = n1;
        if (n0 > best) { best = n0; kb = 2 * k; }       // ascending: first occurrence
        if (n1 > best) { best = n1; kb = 2 * k + 1; }
      }
      const int bidx = base + kb;
      // best >= 0 (squared distances): u64 key ordering == (dist, -idx)
      unsigned long long key =
          ((unsigned long long)__float_as_uint(best) << 32) |
          (unsigned long long)(0xFFFFFFFFu - (unsigned)bidx);

      key = dpp_max_u64<0x111>(key);   // row_shr:1
      key = dpp_max_u64<0x112>(key);   // row_shr:2
      key = dpp_max_u64<0x114>(key);   // row_shr:4
      key = dpp_max_u64<0x118>(key);   // row_shr:8
      key = dpp_max_u64<0x142>(key);   // row_bcast:15
      key = dpp_max_u64<0x143>(key);   // row_bcast:31

      const int par = s & 1;
      if (lane == 63) s_key[par][w] = key;
      __syncthreads();
      unsigned long long kbk = s_key[par][0];
#pragma unroll
      for (int w2 = 1; w2 < 8; w2++) {
        const unsigned long long kk = s_key[par][w2];
        if (kk > kbk) kbk = kk;
      }
      far = (int)(0xFFFFFFFFu - (unsigned)(kbk & 0xFFFFFFFFull));
      fx = X[far];                   // wave-uniform LDS broadcast (conflict-free)
      fy = Y[far];
      fz = Z[far];
    }
    return;
  }

  // ---------------- persistent workers ----------------
  const double wj_tab[5] = {0.16 / (5.0 * 1636.0 * 32.0),
                            0.64 / (5.0 * 1636.0 * 65.0),
                            1.0  / (5.0 * 1636.0 * 81.0),
                            1.44 / (5.0 * 1636.0 * 98.0),
                            2.56 / (5.0 * 1636.0 * 131.0)};

  while (true) {
    __syncthreads();               // protects s_task + task-shared reuse
    if (tid == 0) s_task = atomicAdd(counter, 1);
    __syncthreads();
    const int t = s_task;
    if (t >= NTASKS) return;       // uniform exit

    if (t < REP_TASKS) {
      // ---------------- repulsion task (R12-proven, 512 thr) ----------------
      const int b = t >> 7;                       // 128 tasks per batch
      const int q = ((t & 127) << 6) + lane;
      const float* P = pcd + b * NPTS * 3;

      const float qx = P[q * 3 + 0], qy = P[q * 3 + 1], qz = P[q * 3 + 2];

      int cnt = 0;
      float d0 = 0.0f;
      float t0 = FLT_MAX, t1 = FLT_MAX, t2 = FLT_MAX, t3 = FLT_MAX, t4 = FLT_MAX;

      const int wu = __builtin_amdgcn_readfirstlane(w);
      const float* S = P + wu * SEG_LEN * 3;
#pragma unroll 4
      for (int i = 0; i < SEG_LEN; i++) {
        const float x = S[i * 3 + 0];             // uniform addr -> scalar loads
        const float y = S[i * 3 + 1];
        const float z = S[i * 3 + 2];
        const float dx = qx - x, dy = qy - y, dz = qz - z;
        const float d = dx * dx + dy * dy + dz * dz;
        if (d <= rep_thr && cnt < REP_NS) {
          if (cnt == 0) d0 = d;
          ins5(d, t0, t1, t2, t3, t4);
          cnt++;
        }
      }

      s_t5[w][lane][0] = t0; s_t5[w][lane][1] = t1; s_t5[w][lane][2] = t2;
      s_t5[w][lane][3] = t3; s_t5[w][lane][4] = t4;
      s_d0[w][lane] = d0;
      s_cnt[w][lane] = cnt;
      __syncthreads();

      if (w == 0) {
        int total = 0;
        float fd0 = 0.0f;
        int first_seen = 0;
        float m0 = FLT_MAX, m1 = FLT_MAX, m2 = FLT_MAX, m3 = FLT_MAX, m4 = FLT_MAX;
#pragma unroll
        for (int sg = 0; sg < REP_SEG; sg++) {
          const int c = s_cnt[sg][lane];
          if (c > 0 && !first_seen) { fd0 = s_d0[sg][lane]; first_seen = 1; }
          total += c;
#pragma unroll
          for (int j = 0; j < 5; j++) ins5(s_t5[sg][lane][j], m0, m1, m2, m3, m4);
        }

        if (total > REP_NS) {
          // cap binds across segments (astronomically rare): exact rescan
          int c2 = 0;
          m0 = FLT_MAX; m1 = FLT_MAX; m2 = FLT_MAX; m3 = FLT_MAX; m4 = FLT_MAX;
          for (int i = 0; i < NPTS && c2 < REP_NS; i++) {
            const float dx = qx - P[i * 3 + 0];
            const float dy = qy - P[i * 3 + 1];
            const float dz = qz - P[i * 3 + 2];
            const float d = dx * dx + dy * dy + dz * dz;
            if (d <= rep_thr) { ins5(d, m0, m1, m2, m3, m4); c2++; }
          }
        } else {
          for (int c = total; c < REP_NS; c++) ins5(fd0, m0, m1, m2, m3, m4);
        }

        float sum = rep_term(m1) + rep_term(m2) + rep_term(m3) + rep_term(m4);
#pragma unroll
        for (int off = 32; off >= 1; off >>= 1) sum += __shfl_down(sum, off);
        if (lane == 0) rep_part[t] = (double)sum;
      }
    } else {
      // ---------------- uniform task (R12-proven algorithm, 8 waves) --------
      const int ball = t - REP_TASKS;
      const int b = ball / NPOINT;
      const float* P = pcd + b * NPTS * 3;

      if (tid == 0) {
        int v = __hip_atomic_load(&fps_idx[ball], __ATOMIC_RELAXED,
                                  __HIP_MEMORY_SCOPE_AGENT);
        while (v < 0) {
          __builtin_amdgcn_s_sleep(32);
          v = __hip_atomic_load(&fps_idx[ball], __ATOMIC_RELAXED,
                                __HIP_MEMORY_SCOPE_AGENT);
        }
        s_qidx = v;
      }
      __syncthreads();
      const int qidx = s_qidx;
      const float qx = P[qidx * 3 + 0], qy = P[qidx * 3 + 1], qz = P[qidx * 3 + 2];

      // scan this wave's contiguous 1024-point segment (index order kept)
      int wcnt = 0;
      const float* S = P + w * 1024 * 3;
      for (int it = 0; it < 16; it++) {
        const int j = it * 64 + lane;
        const float x = S[j * 3 + 0];
        const float y = S[j * 3 + 1];
        const float z = S[j * 3 + 2];
        const float dx = qx - x, dy = qy - y, dz = qz - z;
        const float d = dx * dx + dy * dy + dz * dz;
        const bool hit = (d <= up.thr[4]);
        const unsigned long long m = __ballot(hit);
        if (hit) {
          const int pos = wcnt + __popcll(m & ((1ull << lane) - 1ull));
          if (pos < UW) {
            wx[w][pos] = x; wy[w][pos] = y; wz[w][pos] = z; wd[w][pos] = d;
          }
        }
        wcnt += __popcll(m);
      }
      if (lane == 0) s_wcnt[w] = min(wcnt, UW);
      __syncthreads();

      int off = 0;
#pragma unroll
      for (int w2 = 0; w2 < 8; w2++) {
        if (w2 == w) break;
        off += s_wcnt[w2];
      }
      for (int i = lane; i < s_wcnt[w]; i += 64) {
        FX[off + i] = wx[w][i]; FY[off + i] = wy[w][i];
        FZ[off + i] = wz[w][i]; FD[off + i] = wd[w][i];
      }
      __syncthreads();
      int c = 0;
#pragma unroll
      for (int w2 = 0; w2 < 8; w2++) c += s_wcnt[w2];   // >=1 (self hit)

      double local = 0.0;
      if (w < 5) {
        const int jp = w;
        const float thr = up.thr[jp];
        const int nsj = up.ns[jp];

        int cnt2 = 0;
        for (int bse = 0; bse < c; bse += 64) {
          const int e = bse + lane;
          const bool pred = (e < c) && (FD[e] <= thr);
          const unsigned long long m = __ballot(pred);
          if (pred) {
            const int pos = cnt2 + __popcll(m & ((1ull << lane) - 1ull));
            if (pos < nsj) {
              CX[jp][pos] = FX[e]; CY[jp][pos] = FY[e]; CZ[jp][pos] = FZ[e];
            }
          }
          cnt2 += __popcll(m);
        }
        const int cj = min(cnt2, nsj);     // >= 1 (self hit)
        const int pads = nsj - cj;
        const int istart = (pads > 0) ? 1 : 0;

        if (pads > 0 && lane == 0) {
          // pad rows + row 0: second-smallest = 0 exactly
          const float ud = sqrtf(fabsf(1e-8f));
          const float dd = ud - up.e[jp];
          const float tt = (dd * dd) / up.eden[jp];
          local += (double)tt * wj_tab[jp] * (double)(pads + 1);
        }

        for (int r = istart + lane; r < cj; r += 64) {
          const float xi = CX[jp][r], yi = CY[jp][r], zi = CZ[jp][r];
          float m2 = FLT_MAX;
          for (int e2 = 0; e2 < cj; e2++) {
            if (e2 == r) continue;
            const float dx = xi - CX[jp][e2];
            const float dy = yi - CY[jp][e2];
            const float dz = zi - CZ[jp][e2];
            const float d = dx * dx + dy * dy + dz * dz;
            if (d < m2) m2 = d;
          }
          const float ud = sqrtf(fabsf(m2 + 1e-8f));
          const float dd = ud - up.e[jp];
          const float tt = (dd * dd) / up.eden[jp];
          local += (double)tt * wj_tab[jp];
        }
      }

#pragma unroll
      for (int o = 32; o >= 1; o >>= 1) local += __shfl_down(local, o);
      if (lane == 0) dpart[w] = local;
      __syncthreads();
      if (tid == 0) {
        double u = 0.0;
#pragma unroll
        for (int w2 = 0; w2 < 8; w2++) u += dpart[w2];
        uni_part[ball] = u;
      }
    }
  }
}

// ---------------------------------------------------------------- finalize
__global__ __launch_bounds__(256) void fin_kernel(const double* __restrict__ rep_part,
                                                  const double* __restrict__ uni_part,
                                                  float* __restrict__ out) {
  __shared__ double sd[256];
  const int t = threadIdx.x;
  double u = 0.0, r = 0.0;
  for (int i = t; i < NBALLS; i += 256) u += uni_part[i];
  for (int i = t; i < REP_TASKS; i += 256) r += rep_part[i];

  sd[t] = u; __syncthreads();
  for (int s = 128; s > 0; s >>= 1) { if (t < s) sd[t] += sd[t + s]; __syncthreads(); }
  const double usum = sd[0];
  __syncthreads();
  sd[t] = r; __syncthreads();
  for (int s = 128; s > 0; s >>= 1) { if (t < s) sd[t] += sd[t + s]; __syncthreads(); }

  if (t == 0) {
    out[0] = (float)usum;
    out[1] = (float)(sd[0] * (1.0 / 131072.0));
  }
}

// ---------------------------------------------------------------- launch
extern "C" void kernel_launch(void* const* d_in, const int* in_sizes, int n_in,
                              void* d_out, int out_size, void* d_ws, size_t ws_size,
                              hipStream_t stream) {
  (void)in_sizes; (void)n_in; (void)out_size; (void)ws_size;
  const float* pcd = (const float*)d_in[0];
  float* out = (float*)d_out;
  int*    fps      = (int*)((char*)d_ws + WS_FPS_OFF);
  double* rep_part = (double*)((char*)d_ws + WS_REP_OFF);
  double* uni_part = (double*)((char*)d_ws + WS_UNI_OFF);
  int*    counter  = (int*)((char*)d_ws + WS_CNT_OFF);

  const float rep_thr = (float)(0.07 * 0.07);

  UniParams up;
  const double ps[5] = {0.004, 0.008, 0.01, 0.012, 0.016};
  for (int j = 0; j < 5; j++) {
    const int ns = (int)(8192.0 * ps[j]);            // 32, 65, 81, 98, 131
    const double r = sqrt(ps[j]);
    up.thr[j] = (float)(r * r);
    const double disk = M_PI * ps[j] / (double)ns;
    const double el = sqrt(2.0 * disk / 1.732);
    up.e[j] = (float)el;
    up.eden[j] = (float)(el + 1e-8);
    up.ns[j] = ns;
  }

  // sentinel-init fps_idx (0xFF -> negative) and zero the task counter.
  // hipMemsetAsync is stream-ordered and graph-capture safe.
  hipMemsetAsync(fps, 0xFF, NBALLS * sizeof(int), stream);
  hipMemsetAsync(counter, 0, sizeof(int), stream);

  static const int kDynLds = NPTS * 3 * (int)sizeof(float);   // 98304
  (void)hipFuncSetAttribute((const void*)fused_kernel,
                            hipFuncAttributeMaxDynamicSharedMemorySize, kDynLds);

  fused_kernel<<<BATCH + NWORKERS, 512, kDynLds, stream>>>(pcd, fps, rep_part,
                                                           uni_part, counter,
                                                           up, rep_thr);
  fin_kernel<<<1, 256, 0, stream>>>(rep_part, uni_part, out);
}